// Round 10
// baseline (232.494 us; speedup 1.0000x reference)
//
#include <hip/hip_runtime.h>

// MultiheadAttention: bs=2, n_ctx=2048, width=1024, HEADS=16, head_dim=64, fp32 in/out.
// Pipeline: split/transpose converts -> bf16x3 GEMMs (m97 structure: 128^2 tile, BK=32,
// gll16 plane-staged LDS, conflict-free) -> swapped-QK 32x32 flash attention (LDS K/V).

using u16 = unsigned short;
typedef __attribute__((ext_vector_type(8))) short s16x8;    // 8 bf16 = 4 VGPR (MFMA A/B frag)
typedef __attribute__((ext_vector_type(4))) float f32x4;    // 16x16 MFMA C/D frag
typedef __attribute__((ext_vector_type(16))) float f32x16;  // 32x32 MFMA C/D frag

__device__ __forceinline__ u16 f2bf(float f) {
    unsigned x = __builtin_bit_cast(unsigned, f);
    x += 0x7fffu + ((x >> 16) & 1u);            // RNE
    return (u16)(x >> 16);
}
__device__ __forceinline__ float bf2f(u16 u) {
    return __builtin_bit_cast(float, ((unsigned)u) << 16);
}
// pack two f32 -> {lo: bf16(lo), hi: bf16(hi)} with RNE — same numerics as f2bf
// (round-3 post-mortem: v_cvt_pk_bf16_f32 gave absmax 7e-4; keep the verified path).
__device__ __forceinline__ unsigned pk2bf(float lo, float hi) {
    unsigned a = __builtin_bit_cast(unsigned, lo);
    unsigned b = __builtin_bit_cast(unsigned, hi);
    a += 0x7fffu + ((a >> 16) & 1u);
    b += 0x7fffu + ((b >> 16) & 1u);
    return (a >> 16) | (b & 0xffff0000u);
}
// async global->LDS, 16B per lane; LDS dest = uniform base + lane*16 (HW rule).
__device__ __forceinline__ void gll16(const void* g, void* l) {
    __builtin_amdgcn_global_load_lds(
        (const __attribute__((address_space(1))) unsigned int*)g,
        (__attribute__((address_space(3))) unsigned int*)l, 16, 0, 0);
}

#define MFMA(a, b, c)   __builtin_amdgcn_mfma_f32_16x16x32_bf16((a), (b), (c), 0, 0, 0)
#define MFMA32(a, b, c) __builtin_amdgcn_mfma_f32_32x32x16_bf16((a), (b), (c), 0, 0, 0)

// ---------------- converts ----------------

__global__ __launch_bounds__(256) void convert_split(const float* __restrict__ in,
                                                     u16* __restrict__ H, u16* __restrict__ L, int n) {
    int i = (blockIdx.x * 256 + threadIdx.x) * 4;
    if (i >= n) return;
    float4 v = *(const float4*)(in + i);
    u16 h0 = f2bf(v.x), h1 = f2bf(v.y), h2 = f2bf(v.z), h3 = f2bf(v.w);
    ushort4 hh = { h0, h1, h2, h3 };
    ushort4 ll = { f2bf(v.x - bf2f(h0)), f2bf(v.y - bf2f(h1)), f2bf(v.z - bf2f(h2)), f2bf(v.w - bf2f(h3)) };
    *(ushort4*)(H + i) = hh;
    *(ushort4*)(L + i) = ll;
}

// W[K][N] fp32 -> WT[N][K] bf16 hi/lo.
__global__ __launch_bounds__(256) void transpose_split(const float* __restrict__ W,
                                                       u16* __restrict__ TH, u16* __restrict__ TL,
                                                       int K, int N) {
    __shared__ float st[32][33];
    int n0 = blockIdx.x * 32, k0 = blockIdx.y * 32;
    int c = threadIdx.x & 31, r8 = threadIdx.x >> 5;
#pragma unroll
    for (int i = 0; i < 4; ++i) {
        int r = r8 + i * 8;
        st[r][c] = W[(size_t)(k0 + r) * N + n0 + c];
    }
    __syncthreads();
#pragma unroll
    for (int i = 0; i < 4; ++i) {
        int r = r8 + i * 8;
        float v = st[c][r];
        u16 h = f2bf(v);
        TH[(size_t)(n0 + r) * K + k0 + c] = h;
        TL[(size_t)(n0 + r) * K + k0 + c] = f2bf(v - bf2f(h));
    }
}

// ---------------- bf16x3 GEMM: m97 structure (128^2 tile, BK=32, 4 waves) ----------------
// LDS: 32 planes x 1KB (single-buffered, 32KB -> 3-4 blocks/CU for m114 cross-block overlap).
// Plane p: array p>>3 (0 Ah, 1 Al, 2 Bh, 3 Bl), 16-row subtile p&7, laid [g][c16][8]
// -> frag read at lane*16B, conflict-free; gll16 dest lane-linear, per-lane permuted SOURCE
// carries the layout (m173 pattern; R8-verified correct, conflicts==0).
// Schedule per kt (m97 2-barrier): sync (prev reads done) ; stage 8 gll/wave ; sync
// (vmcnt drained -> planes landed) ; ds_read frags ; 48 MFMA (setprio, T5).
// EPI 0: QKV epilogue -> Qs (scaled log2e/8), K, Vp (sigma-permuted). EPI 1: fp32 out + bias.

template <int EPI>
__global__ __launch_bounds__(256, 3) void gemm_bf16x3(
    const u16* __restrict__ AH, const u16* __restrict__ AL,
    const u16* __restrict__ BTH, const u16* __restrict__ BTL,
    const float* __restrict__ bias,
    u16* __restrict__ Qs, u16* __restrict__ Kb, u16* __restrict__ Vp,
    float* __restrict__ Out) {
    __shared__ u16 sP[32][512];   // 32 KiB

    int m0 = blockIdx.y * 128, n0 = blockIdx.x * 128;
    int tid = threadIdx.x, lane = tid & 63, wv = tid >> 6;
    int g = lane >> 4, c16 = lane & 15;
    int wm = wv >> 1, wn = wv & 1;
    const int lo8 = lane * 8;

    // per-lane global sources for this wave's 8 planes (R8-verified mapping)
    const u16* src[8];
#pragma unroll
    for (int i = 0; i < 8; ++i) {
        int p = wv * 8 + i;
        const u16* arr = (p < 8) ? AH : (p < 16) ? AL : (p < 24) ? BTH : BTL;
        int row0 = ((p < 16) ? m0 : n0) + (p & 7) * 16;
        src[i] = arr + (size_t)(row0 + c16) * 1024 + g * 8;
    }

    f32x4 acc[4][4] = {};

    for (int kt = 0; kt < 32; ++kt) {
        __syncthreads();                     // prior reads of sP complete
        int ko = kt * 32;
#pragma unroll
        for (int i = 0; i < 8; ++i) gll16(src[i] + ko, &sP[wv * 8 + i][0]);
        __syncthreads();                     // vmcnt drained: planes landed

        s16x8 ah[4], al[4], bh[4], bl[4];
#pragma unroll
        for (int mi = 0; mi < 4; ++mi) {
            ah[mi] = *(const s16x8*)&sP[wm * 4 + mi][lo8];
            al[mi] = *(const s16x8*)&sP[8 + wm * 4 + mi][lo8];
        }
#pragma unroll
        for (int ni = 0; ni < 4; ++ni) {
            bh[ni] = *(const s16x8*)&sP[16 + wn * 4 + ni][lo8];
            bl[ni] = *(const s16x8*)&sP[24 + wn * 4 + ni][lo8];
        }
        __builtin_amdgcn_s_setprio(1);
#pragma unroll
        for (int mi = 0; mi < 4; ++mi)
#pragma unroll
            for (int ni = 0; ni < 4; ++ni) {
                f32x4 c = acc[mi][ni];
                c = MFMA(ah[mi], bh[ni], c);
                c = MFMA(al[mi], bh[ni], c);
                c = MFMA(ah[mi], bl[ni], c);
                acc[mi][ni] = c;
            }
        __builtin_amdgcn_s_setprio(0);
    }

    // C/D layout: col = lane&15, row = 4*(lane>>4)+reg
#pragma unroll
    for (int ni = 0; ni < 4; ++ni) {
        int col = n0 + wn * 64 + ni * 16 + c16;
        float bs = bias[col];
        if (EPI == 0) {
            int h = col / 192;
            int rm = col - h * 192;
#pragma unroll
            for (int mi = 0; mi < 4; ++mi)
#pragma unroll
                for (int r = 0; r < 4; ++r) {
                    int row = m0 + wm * 64 + mi * 16 + 4 * g + r;
                    int b = row >> 11, s = row & 2047;
                    int bh16 = b * 16 + h;
                    float val = acc[mi][ni][r] + bs;
                    if (rm < 64)
                        // 1/8 softmax scale folded with log2(e) so attn can use exp2
                        Qs[(((size_t)bh16 * 2048 + s) << 6) + rm] = f2bf(val * 0.18033688011112042f);
                    else if (rm < 128)
                        Kb[(((size_t)bh16 * 2048 + s) << 6) + rm - 64] = f2bf(val);
                    else {
                        // sigma-permuted V: Vp[bh][s/16][d][m], kv = 16*(s/16)+sigma(m),
                        // sigma(m) = (m&3) + 8*((m>>2)&1) + 4*(m>>3)
                        int d = rm - 128;
                        int kg = s >> 4, k16 = s & 15;
                        int mm = (k16 & 3) | (((k16 >> 3) & 1) << 2) | (((k16 >> 2) & 1) << 3);
                        Vp[(((size_t)bh16 * 128 + kg) * 64 + d) * 16 + mm] = f2bf(val);
                    }
                }
        } else {
#pragma unroll
            for (int mi = 0; mi < 4; ++mi)
#pragma unroll
                for (int r = 0; r < 4; ++r) {
                    int row = m0 + wm * 64 + mi * 16 + 4 * g + r;
                    Out[(size_t)row * 1024 + col] = acc[mi][ni][r] + bs;
                }
        }
    }
}

// ---------------- flash attention: LDS-shared K/V, swapped-QK 32x32 MFMA (R7, verified) --------
__global__ __launch_bounds__(256, 2) void attn_fwd(
    const u16* __restrict__ Qs, const u16* __restrict__ Kb, const u16* __restrict__ Vp,
    u16* __restrict__ OH, u16* __restrict__ OL) {
    __shared__ u16 sKV[2][16][512];

    int id = blockIdx.x;
    int xcd = id & 7, li = id >> 3;          // 4 heads per XCD -> K/V (2MB) stays L2-resident
    int bh = xcd * 4 + (li >> 4);
    int qblk = li & 15;
    int tid = threadIdx.x, w = tid >> 6, lane = tid & 63;
    int l31 = lane & 31, h = lane >> 5;
    int q0 = (qblk * 4 + w) * 32;

    size_t base = (size_t)bh * 2048 * 64;
    size_t vbase = (size_t)bh * 131072;       // 128*64*16

    const u16* qp = Qs + base + (size_t)(q0 + l31) * 64 + 8 * h;
    s16x8 qf[4];
#pragma unroll
    for (int c = 0; c < 4; ++c) qf[c] = *(const s16x8*)(qp + 16 * c);

    const int pk0 = 2 * w, pk1 = 2 * w + 1;
    const u16* gk0 = Kb + base + (size_t)((pk0 >> 2) * 32 + l31) * 64 + 16 * (pk0 & 3) + 8 * h;
    const u16* gk1 = Kb + base + (size_t)((pk1 >> 2) * 32 + l31) * 64 + 16 * (pk1 & 3) + 8 * h;
    const u16* gv0 = Vp + vbase + (size_t)pk0 * 512 + (size_t)l31 * 16 + 8 * h;
    const u16* gv1 = Vp + vbase + (size_t)pk1 * 512 + (size_t)l31 * 16 + 8 * h;

    auto stage = [&](int buf, int jj) {
        size_t ko = (size_t)jj * 4096;        // 64 kv rows * 64 d
        gll16(gk0 + ko, &sKV[buf][pk0][0]);
        gll16(gk1 + ko, &sKV[buf][pk1][0]);
        gll16(gv0 + ko, &sKV[buf][8 + pk0][0]);
        gll16(gv1 + ko, &sKV[buf][8 + pk1][0]);
    };

    f32x16 o0 = {}, o1 = {};
    float m = -1e30f, ls = 0.f;
    const int lo = lane * 8;

    stage(0, 0);

    for (int jj = 0; jj < 32; ++jj) {
        int cur = jj & 1;
        __syncthreads();
        if (jj < 31) stage(cur ^ 1, jj + 1);

        s16x8 kf[8], vf[8];
#pragma unroll
        for (int i = 0; i < 8; ++i) {
            kf[i] = *(const s16x8*)&sKV[cur][i][lo];
            vf[i] = *(const s16x8*)&sKV[cur][8 + i][lo];
        }

        f32x16 s0 = {}, s1 = {};
        __builtin_amdgcn_s_setprio(1);
        s0 = MFMA32(kf[0], qf[0], s0);
        s0 = MFMA32(kf[1], qf[1], s0);
        s0 = MFMA32(kf[2], qf[2], s0);
        s0 = MFMA32(kf[3], qf[3], s0);
        s1 = MFMA32(kf[4], qf[0], s1);
        s1 = MFMA32(kf[5], qf[1], s1);
        s1 = MFMA32(kf[6], qf[2], s1);
        s1 = MFMA32(kf[7], qf[3], s1);
        __builtin_amdgcn_s_setprio(0);

        float t0 = fmaxf(s0[0], s1[0]), t1 = fmaxf(s0[1], s1[1]);
        float t2 = fmaxf(s0[2], s1[2]), t3 = fmaxf(s0[3], s1[3]);
#pragma unroll
        for (int r = 4; r < 16; r += 4) {
            t0 = fmaxf(t0, fmaxf(s0[r], s1[r]));
            t1 = fmaxf(t1, fmaxf(s0[r + 1], s1[r + 1]));
            t2 = fmaxf(t2, fmaxf(s0[r + 2], s1[r + 2]));
            t3 = fmaxf(t3, fmaxf(s0[r + 3], s1[r + 3]));
        }
        float pmax = fmaxf(fmaxf(t0, t1), fmaxf(t2, t3));
        pmax = fmaxf(pmax, __shfl_xor(pmax, 32));

        if (!__all(pmax <= m + 8.f)) {          // defer-max (T13), log2 units
            float mn = fmaxf(m, pmax);
            float f = __builtin_amdgcn_exp2f(m - mn);
            m = mn;
            ls *= f;
#pragma unroll
            for (int r = 0; r < 16; ++r) {
                float fb = __shfl(f, (r & 3) + 8 * (r >> 2) + 4 * h);
                o0[r] *= fb;
                o1[r] *= fb;
            }
        }

        float a0 = 0.f, a1 = 0.f, a2 = 0.f, a3 = 0.f;
#pragma unroll
        for (int r = 0; r < 16; r += 4) {
            s0[r]     = __builtin_amdgcn_exp2f(s0[r] - m);     a0 += s0[r];
            s0[r + 1] = __builtin_amdgcn_exp2f(s0[r + 1] - m); a1 += s0[r + 1];
            s0[r + 2] = __builtin_amdgcn_exp2f(s0[r + 2] - m); a2 += s0[r + 2];
            s0[r + 3] = __builtin_amdgcn_exp2f(s0[r + 3] - m); a3 += s0[r + 3];
            s1[r]     = __builtin_amdgcn_exp2f(s1[r] - m);     a0 += s1[r];
            s1[r + 1] = __builtin_amdgcn_exp2f(s1[r + 1] - m); a1 += s1[r + 1];
            s1[r + 2] = __builtin_amdgcn_exp2f(s1[r + 2] - m); a2 += s1[r + 2];
            s1[r + 3] = __builtin_amdgcn_exp2f(s1[r + 3] - m); a3 += s1[r + 3];
        }
        float sm = (a0 + a1) + (a2 + a3);
        sm += __shfl_xor(sm, 32);
        ls += sm;

        union { s16x8 v8; unsigned u[4]; } p00, p01, p10, p11;
#pragma unroll
        for (int k = 0; k < 4; ++k) {
            p00.u[k] = pk2bf(s0[2 * k], s0[2 * k + 1]);
            p01.u[k] = pk2bf(s0[8 + 2 * k], s0[9 + 2 * k]);
            p10.u[k] = pk2bf(s1[2 * k], s1[2 * k + 1]);
            p11.u[k] = pk2bf(s1[8 + 2 * k], s1[9 + 2 * k]);
        }

        __builtin_amdgcn_s_setprio(1);
        o0 = MFMA32(p00.v8, vf[0], o0);
        o1 = MFMA32(p00.v8, vf[1], o1);
        o0 = MFMA32(p01.v8, vf[2], o0);
        o1 = MFMA32(p01.v8, vf[3], o1);
        o0 = MFMA32(p10.v8, vf[4], o0);
        o1 = MFMA32(p10.v8, vf[5], o1);
        o0 = MFMA32(p11.v8, vf[6], o0);
        o1 = MFMA32(p11.v8, vf[7], o1);
        __builtin_amdgcn_s_setprio(0);
    }

    int b = bh >> 4, hh = bh & 15;
    float inv = 1.0f / ls;
#pragma unroll
    for (int r = 0; r < 16; ++r) {
        int cr = (r & 3) + 8 * (r >> 2) + 4 * h;
        float fb = __shfl(inv, cr);
        int row = q0 + cr;
        size_t idx = ((size_t)(b * 2048 + row)) * 1024 + hh * 64 + l31;
        float v0 = o0[r] * fb, v1 = o1[r] * fb;
        u16 h0 = f2bf(v0);
        OH[idx] = h0;
        OL[idx] = f2bf(v0 - bf2f(h0));
        u16 h1 = f2bf(v1);
        OH[idx + 32] = h1;
        OL[idx + 32] = f2bf(v1 - bf2f(h1));
    }
}

// ---------------- launch ----------------

extern "C" void kernel_launch(void* const* d_in, const int* in_sizes, int n_in,
                              void* d_out, int out_size, void* d_ws, size_t ws_size,
                              hipStream_t stream) {
    const float* x     = (const float*)d_in[0];
    const float* Wqkv  = (const float*)d_in[1];
    const float* bqkv  = (const float*)d_in[2];
    const float* Wproj = (const float*)d_in[3];
    const float* bproj = (const float*)d_in[4];
    float* out = (float*)d_out;

    char* w = (char*)d_ws;
    const size_t SZ_X  = (size_t)4096 * 1024 * 2;  // 8 MiB (bf16)
    const size_t SZ_WQ = (size_t)3072 * 1024 * 2;
    const size_t SZ_WP = (size_t)1024 * 1024 * 2;
    u16* XH  = (u16*)w; w += SZ_X;
    u16* XL  = (u16*)w; w += SZ_X;
    u16* WQH = (u16*)w; w += SZ_WQ;
    u16* WQL = (u16*)w; w += SZ_WQ;
    u16* WPH = (u16*)w; w += SZ_WP;
    u16* WPL = (u16*)w; w += SZ_WP;
    u16* Q_s = (u16*)w; w += SZ_X;                  // [bh][s][64] scaled by log2e/8
    u16* K_b = (u16*)w; w += SZ_X;                  // [bh][s][64]
    u16* V_p = (u16*)w; w += SZ_X;                  // [bh][s/16][64][16] sigma-permuted
    u16* OHp = (u16*)w; w += SZ_X;                  // attn out hi [4096][1024]
    u16* OLp = (u16*)w; w += SZ_X;                  // attn out lo

    convert_split<<<4096, 256, 0, stream>>>(x, XH, XL, 4096 * 1024);
    transpose_split<<<dim3(96, 32), 256, 0, stream>>>(Wqkv, WQH, WQL, 1024, 3072);
    transpose_split<<<dim3(32, 32), 256, 0, stream>>>(Wproj, WPH, WPL, 1024, 1024);
    gemm_bf16x3<0><<<dim3(24, 32), 256, 0, stream>>>(XH, XL, WQH, WQL, bqkv, Q_s, K_b, V_p, nullptr);
    attn_fwd<<<512, 256, 0, stream>>>(Q_s, K_b, V_p, OHp, OLp);
    gemm_bf16x3<1><<<dim3(8, 32), 256, 0, stream>>>(OHp, OLp, WPH, WPL, bproj, nullptr, nullptr, nullptr, out);
}

// Round 11
// 201.112 us; speedup vs baseline: 1.1560x; 1.1560x over previous
//
#include <hip/hip_runtime.h>

// MultiheadAttention: bs=2, n_ctx=2048, width=1024, HEADS=16, head_dim=64, fp32 in/out.
// Pipeline: split/transpose converts -> bf16x3 GEMMs (R7 structure + prefetch-next-kt
// software pipeline) -> swapped-QK 32x32 flash attention (LDS-shared K/V, R7 verbatim).

using u16 = unsigned short;
typedef __attribute__((ext_vector_type(8))) short s16x8;    // 8 bf16 = 4 VGPR (MFMA A/B frag)
typedef __attribute__((ext_vector_type(4))) float f32x4;    // 16x16 MFMA C/D frag
typedef __attribute__((ext_vector_type(16))) float f32x16;  // 32x32 MFMA C/D frag

__device__ __forceinline__ u16 f2bf(float f) {
    unsigned x = __builtin_bit_cast(unsigned, f);
    x += 0x7fffu + ((x >> 16) & 1u);            // RNE
    return (u16)(x >> 16);
}
__device__ __forceinline__ float bf2f(u16 u) {
    return __builtin_bit_cast(float, ((unsigned)u) << 16);
}
// pack two f32 -> {lo: bf16(lo), hi: bf16(hi)} with RNE — same numerics as f2bf
// (round-3 post-mortem: v_cvt_pk_bf16_f32 gave absmax 7e-4; keep the verified path).
__device__ __forceinline__ unsigned pk2bf(float lo, float hi) {
    unsigned a = __builtin_bit_cast(unsigned, lo);
    unsigned b = __builtin_bit_cast(unsigned, hi);
    a += 0x7fffu + ((a >> 16) & 1u);
    b += 0x7fffu + ((b >> 16) & 1u);
    return (a >> 16) | (b & 0xffff0000u);
}
// async global->LDS, 16B per lane; LDS dest = uniform base + lane*16 (HW rule).
__device__ __forceinline__ void gll16(const void* g, void* l) {
    __builtin_amdgcn_global_load_lds(
        (const __attribute__((address_space(1))) unsigned int*)g,
        (__attribute__((address_space(3))) unsigned int*)l, 16, 0, 0);
}

#define MFMA(a, b, c)   __builtin_amdgcn_mfma_f32_16x16x32_bf16((a), (b), (c), 0, 0, 0)
#define MFMA32(a, b, c) __builtin_amdgcn_mfma_f32_32x32x16_bf16((a), (b), (c), 0, 0, 0)

// ---------------- converts ----------------

__global__ __launch_bounds__(256) void convert_split(const float* __restrict__ in,
                                                     u16* __restrict__ H, u16* __restrict__ L, int n) {
    int i = (blockIdx.x * 256 + threadIdx.x) * 4;
    if (i >= n) return;
    float4 v = *(const float4*)(in + i);
    u16 h0 = f2bf(v.x), h1 = f2bf(v.y), h2 = f2bf(v.z), h3 = f2bf(v.w);
    ushort4 hh = { h0, h1, h2, h3 };
    ushort4 ll = { f2bf(v.x - bf2f(h0)), f2bf(v.y - bf2f(h1)), f2bf(v.z - bf2f(h2)), f2bf(v.w - bf2f(h3)) };
    *(ushort4*)(H + i) = hh;
    *(ushort4*)(L + i) = ll;
}

// W[K][N] fp32 -> WT[N][K] bf16 hi/lo.
__global__ __launch_bounds__(256) void transpose_split(const float* __restrict__ W,
                                                       u16* __restrict__ TH, u16* __restrict__ TL,
                                                       int K, int N) {
    __shared__ float st[32][33];
    int n0 = blockIdx.x * 32, k0 = blockIdx.y * 32;
    int c = threadIdx.x & 31, r8 = threadIdx.x >> 5;
#pragma unroll
    for (int i = 0; i < 4; ++i) {
        int r = r8 + i * 8;
        st[r][c] = W[(size_t)(k0 + r) * N + n0 + c];
    }
    __syncthreads();
#pragma unroll
    for (int i = 0; i < 4; ++i) {
        int r = r8 + i * 8;
        float v = st[c][r];
        u16 h = f2bf(v);
        TH[(size_t)(n0 + r) * K + k0 + c] = h;
        TL[(size_t)(n0 + r) * K + k0 + c] = f2bf(v - bf2f(h));
    }
}

// ---------------- bf16x3 GEMM (128x128 tile, BK=32, 4 waves) ----------------
// R7 structure + prefetch pipeline: loads for kt+1 issue AFTER barrier2 of kt, BEFORE the
// 48-MFMA compute of kt, so the ~300cy global latency hides under compute (R10 post-mortem:
// the gll16 {sync;stage;sync} variant fully exposes that latency per kt -> 26% MfmaUtil).
// Compiler places vmcnt waits before the next iteration's ds_write automatically.
// EPI 0: QKV epilogue -> Qs (scaled log2e/8), K, Vp (sigma-permuted). EPI 1: fp32 out + bias.

template <int EPI>
__global__ __launch_bounds__(256, 2) void gemm_bf16x3(
    const u16* __restrict__ AH, const u16* __restrict__ AL,
    const u16* __restrict__ BTH, const u16* __restrict__ BTL,
    const float* __restrict__ bias,
    u16* __restrict__ Qs, u16* __restrict__ Kb, u16* __restrict__ Vp,
    float* __restrict__ Out) {
    const int K = 1024;
    __shared__ u16 sAh[128][40], sAl[128][40], sBh[128][40], sBl[128][40];

    int m0 = blockIdx.y * 128, n0 = blockIdx.x * 128;
    int tid = threadIdx.x, lane = tid & 63, wv = tid >> 6;
    int g = lane >> 4, c16 = lane & 15;
    int wm = wv >> 1, wn = wv & 1;

    // per-thread staging coordinates (loop-invariant)
    int rr0 = tid >> 2, rr1 = (256 + tid) >> 2;
    int ko0 = (tid & 3) * 8, ko1 = ((256 + tid) & 3) * 8;
    const u16* pa0  = AH  + (size_t)(m0 + rr0) * K + ko0;
    const u16* pa1  = AH  + (size_t)(m0 + rr1) * K + ko1;
    const u16* pla0 = AL  + (size_t)(m0 + rr0) * K + ko0;
    const u16* pla1 = AL  + (size_t)(m0 + rr1) * K + ko1;
    const u16* pb0  = BTH + (size_t)(n0 + rr0) * K + ko0;
    const u16* pb1  = BTH + (size_t)(n0 + rr1) * K + ko1;
    const u16* plb0 = BTL + (size_t)(n0 + rr0) * K + ko0;
    const u16* plb1 = BTL + (size_t)(n0 + rr1) * K + ko1;

    f32x4 acc[4][4] = {};

    s16x8 ra[2], rla[2], rb[2], rlb[2];
    // preload kt=0
    ra[0]  = *(const s16x8*)(pa0);  ra[1]  = *(const s16x8*)(pa1);
    rla[0] = *(const s16x8*)(pla0); rla[1] = *(const s16x8*)(pla1);
    rb[0]  = *(const s16x8*)(pb0);  rb[1]  = *(const s16x8*)(pb1);
    rlb[0] = *(const s16x8*)(plb0); rlb[1] = *(const s16x8*)(plb1);

    for (int kt = 0; kt < 32; ++kt) {
        __syncthreads();                     // waves done reading LDS tile kt-1
        *(s16x8*)&sAh[rr0][ko0] = ra[0];
        *(s16x8*)&sAh[rr1][ko1] = ra[1];
        *(s16x8*)&sAl[rr0][ko0] = rla[0];
        *(s16x8*)&sAl[rr1][ko1] = rla[1];
        *(s16x8*)&sBh[rr0][ko0] = rb[0];
        *(s16x8*)&sBh[rr1][ko1] = rb[1];
        *(s16x8*)&sBl[rr0][ko0] = rlb[0];
        *(s16x8*)&sBl[rr1][ko1] = rlb[1];
        __syncthreads();                     // tile kt visible to all waves

        if (kt < 31) {                       // prefetch kt+1: latency hides under compute
            int ko = (kt + 1) * 32;
            ra[0]  = *(const s16x8*)(pa0 + ko);  ra[1]  = *(const s16x8*)(pa1 + ko);
            rla[0] = *(const s16x8*)(pla0 + ko); rla[1] = *(const s16x8*)(pla1 + ko);
            rb[0]  = *(const s16x8*)(pb0 + ko);  rb[1]  = *(const s16x8*)(pb1 + ko);
            rlb[0] = *(const s16x8*)(plb0 + ko); rlb[1] = *(const s16x8*)(plb1 + ko);
        }

        s16x8 ah[4], al[4], bh[4], bl[4];
#pragma unroll
        for (int mi = 0; mi < 4; ++mi) {
            ah[mi] = *(const s16x8*)&sAh[wm * 64 + mi * 16 + c16][g * 8];
            al[mi] = *(const s16x8*)&sAl[wm * 64 + mi * 16 + c16][g * 8];
        }
#pragma unroll
        for (int ni = 0; ni < 4; ++ni) {
            bh[ni] = *(const s16x8*)&sBh[wn * 64 + ni * 16 + c16][g * 8];
            bl[ni] = *(const s16x8*)&sBl[wn * 64 + ni * 16 + c16][g * 8];
        }
        __builtin_amdgcn_s_setprio(1);
#pragma unroll
        for (int mi = 0; mi < 4; ++mi)
#pragma unroll
            for (int ni = 0; ni < 4; ++ni) {
                f32x4 c = acc[mi][ni];
                c = MFMA(ah[mi], bh[ni], c);
                c = MFMA(al[mi], bh[ni], c);
                c = MFMA(ah[mi], bl[ni], c);
                acc[mi][ni] = c;
            }
        __builtin_amdgcn_s_setprio(0);
    }

    // C/D layout: col = lane&15, row = 4*(lane>>4)+reg
#pragma unroll
    for (int ni = 0; ni < 4; ++ni) {
        int col = n0 + wn * 64 + ni * 16 + c16;
        float bs = bias[col];
        if (EPI == 0) {
            int h = col / 192;
            int rm = col - h * 192;
#pragma unroll
            for (int mi = 0; mi < 4; ++mi)
#pragma unroll
                for (int r = 0; r < 4; ++r) {
                    int row = m0 + wm * 64 + mi * 16 + 4 * g + r;
                    int b = row >> 11, s = row & 2047;
                    int bh16 = b * 16 + h;
                    float val = acc[mi][ni][r] + bs;
                    if (rm < 64)
                        // 1/8 softmax scale folded with log2(e) so attn can use exp2
                        Qs[(((size_t)bh16 * 2048 + s) << 6) + rm] = f2bf(val * 0.18033688011112042f);
                    else if (rm < 128)
                        Kb[(((size_t)bh16 * 2048 + s) << 6) + rm - 64] = f2bf(val);
                    else {
                        // sigma-permuted V: Vp[bh][s/16][d][m], kv = 16*(s/16)+sigma(m),
                        // sigma(m) = (m&3) + 8*((m>>2)&1) + 4*(m>>3)
                        int d = rm - 128;
                        int kg = s >> 4, k16 = s & 15;
                        int mm = (k16 & 3) | (((k16 >> 3) & 1) << 2) | (((k16 >> 2) & 1) << 3);
                        Vp[(((size_t)bh16 * 128 + kg) * 64 + d) * 16 + mm] = f2bf(val);
                    }
                }
        } else {
#pragma unroll
            for (int mi = 0; mi < 4; ++mi)
#pragma unroll
                for (int r = 0; r < 4; ++r) {
                    int row = m0 + wm * 64 + mi * 16 + 4 * g + r;
                    Out[(size_t)row * 1024 + col] = acc[mi][ni][r] + bs;
                }
        }
    }
}

// ---------------- flash attention: LDS-shared K/V, swapped-QK 32x32 MFMA (R7, verified) --------
__global__ __launch_bounds__(256, 2) void attn_fwd(
    const u16* __restrict__ Qs, const u16* __restrict__ Kb, const u16* __restrict__ Vp,
    u16* __restrict__ OH, u16* __restrict__ OL) {
    __shared__ u16 sKV[2][16][512];

    int id = blockIdx.x;
    int xcd = id & 7, li = id >> 3;          // 4 heads per XCD -> K/V (2MB) stays L2-resident
    int bh = xcd * 4 + (li >> 4);
    int qblk = li & 15;
    int tid = threadIdx.x, w = tid >> 6, lane = tid & 63;
    int l31 = lane & 31, h = lane >> 5;
    int q0 = (qblk * 4 + w) * 32;

    size_t base = (size_t)bh * 2048 * 64;
    size_t vbase = (size_t)bh * 131072;       // 128*64*16

    const u16* qp = Qs + base + (size_t)(q0 + l31) * 64 + 8 * h;
    s16x8 qf[4];
#pragma unroll
    for (int c = 0; c < 4; ++c) qf[c] = *(const s16x8*)(qp + 16 * c);

    const int pk0 = 2 * w, pk1 = 2 * w + 1;
    const u16* gk0 = Kb + base + (size_t)((pk0 >> 2) * 32 + l31) * 64 + 16 * (pk0 & 3) + 8 * h;
    const u16* gk1 = Kb + base + (size_t)((pk1 >> 2) * 32 + l31) * 64 + 16 * (pk1 & 3) + 8 * h;
    const u16* gv0 = Vp + vbase + (size_t)pk0 * 512 + (size_t)l31 * 16 + 8 * h;
    const u16* gv1 = Vp + vbase + (size_t)pk1 * 512 + (size_t)l31 * 16 + 8 * h;

    auto stage = [&](int buf, int jj) {
        size_t ko = (size_t)jj * 4096;        // 64 kv rows * 64 d
        gll16(gk0 + ko, &sKV[buf][pk0][0]);
        gll16(gk1 + ko, &sKV[buf][pk1][0]);
        gll16(gv0 + ko, &sKV[buf][8 + pk0][0]);
        gll16(gv1 + ko, &sKV[buf][8 + pk1][0]);
    };

    f32x16 o0 = {}, o1 = {};
    float m = -1e30f, ls = 0.f;
    const int lo = lane * 8;

    stage(0, 0);

    for (int jj = 0; jj < 32; ++jj) {
        int cur = jj & 1;
        __syncthreads();
        if (jj < 31) stage(cur ^ 1, jj + 1);

        s16x8 kf[8], vf[8];
#pragma unroll
        for (int i = 0; i < 8; ++i) {
            kf[i] = *(const s16x8*)&sKV[cur][i][lo];
            vf[i] = *(const s16x8*)&sKV[cur][8 + i][lo];
        }

        f32x16 s0 = {}, s1 = {};
        __builtin_amdgcn_s_setprio(1);
        s0 = MFMA32(kf[0], qf[0], s0);
        s0 = MFMA32(kf[1], qf[1], s0);
        s0 = MFMA32(kf[2], qf[2], s0);
        s0 = MFMA32(kf[3], qf[3], s0);
        s1 = MFMA32(kf[4], qf[0], s1);
        s1 = MFMA32(kf[5], qf[1], s1);
        s1 = MFMA32(kf[6], qf[2], s1);
        s1 = MFMA32(kf[7], qf[3], s1);
        __builtin_amdgcn_s_setprio(0);

        float t0 = fmaxf(s0[0], s1[0]), t1 = fmaxf(s0[1], s1[1]);
        float t2 = fmaxf(s0[2], s1[2]), t3 = fmaxf(s0[3], s1[3]);
#pragma unroll
        for (int r = 4; r < 16; r += 4) {
            t0 = fmaxf(t0, fmaxf(s0[r], s1[r]));
            t1 = fmaxf(t1, fmaxf(s0[r + 1], s1[r + 1]));
            t2 = fmaxf(t2, fmaxf(s0[r + 2], s1[r + 2]));
            t3 = fmaxf(t3, fmaxf(s0[r + 3], s1[r + 3]));
        }
        float pmax = fmaxf(fmaxf(t0, t1), fmaxf(t2, t3));
        pmax = fmaxf(pmax, __shfl_xor(pmax, 32));

        if (!__all(pmax <= m + 8.f)) {          // defer-max (T13), log2 units
            float mn = fmaxf(m, pmax);
            float f = __builtin_amdgcn_exp2f(m - mn);
            m = mn;
            ls *= f;
#pragma unroll
            for (int r = 0; r < 16; ++r) {
                float fb = __shfl(f, (r & 3) + 8 * (r >> 2) + 4 * h);
                o0[r] *= fb;
                o1[r] *= fb;
            }
        }

        float a0 = 0.f, a1 = 0.f, a2 = 0.f, a3 = 0.f;
#pragma unroll
        for (int r = 0; r < 16; r += 4) {
            s0[r]     = __builtin_amdgcn_exp2f(s0[r] - m);     a0 += s0[r];
            s0[r + 1] = __builtin_amdgcn_exp2f(s0[r + 1] - m); a1 += s0[r + 1];
            s0[r + 2] = __builtin_amdgcn_exp2f(s0[r + 2] - m); a2 += s0[r + 2];
            s0[r + 3] = __builtin_amdgcn_exp2f(s0[r + 3] - m); a3 += s0[r + 3];
            s1[r]     = __builtin_amdgcn_exp2f(s1[r] - m);     a0 += s1[r];
            s1[r + 1] = __builtin_amdgcn_exp2f(s1[r + 1] - m); a1 += s1[r + 1];
            s1[r + 2] = __builtin_amdgcn_exp2f(s1[r + 2] - m); a2 += s1[r + 2];
            s1[r + 3] = __builtin_amdgcn_exp2f(s1[r + 3] - m); a3 += s1[r + 3];
        }
        float sm = (a0 + a1) + (a2 + a3);
        sm += __shfl_xor(sm, 32);
        ls += sm;

        union { s16x8 v8; unsigned u[4]; } p00, p01, p10, p11;
#pragma unroll
        for (int k = 0; k < 4; ++k) {
            p00.u[k] = pk2bf(s0[2 * k], s0[2 * k + 1]);
            p01.u[k] = pk2bf(s0[8 + 2 * k], s0[9 + 2 * k]);
            p10.u[k] = pk2bf(s1[2 * k], s1[2 * k + 1]);
            p11.u[k] = pk2bf(s1[8 + 2 * k], s1[9 + 2 * k]);
        }

        __builtin_amdgcn_s_setprio(1);
        o0 = MFMA32(p00.v8, vf[0], o0);
        o1 = MFMA32(p00.v8, vf[1], o1);
        o0 = MFMA32(p01.v8, vf[2], o0);
        o1 = MFMA32(p01.v8, vf[3], o1);
        o0 = MFMA32(p10.v8, vf[4], o0);
        o1 = MFMA32(p10.v8, vf[5], o1);
        o0 = MFMA32(p11.v8, vf[6], o0);
        o1 = MFMA32(p11.v8, vf[7], o1);
        __builtin_amdgcn_s_setprio(0);
    }

    int b = bh >> 4, hh = bh & 15;
    float inv = 1.0f / ls;
#pragma unroll
    for (int r = 0; r < 16; ++r) {
        int cr = (r & 3) + 8 * (r >> 2) + 4 * h;
        float fb = __shfl(inv, cr);
        int row = q0 + cr;
        size_t idx = ((size_t)(b * 2048 + row)) * 1024 + hh * 64 + l31;
        float v0 = o0[r] * fb, v1 = o1[r] * fb;
        u16 h0 = f2bf(v0);
        OH[idx] = h0;
        OL[idx] = f2bf(v0 - bf2f(h0));
        u16 h1 = f2bf(v1);
        OH[idx + 32] = h1;
        OL[idx + 32] = f2bf(v1 - bf2f(h1));
    }
}

// ---------------- launch ----------------

extern "C" void kernel_launch(void* const* d_in, const int* in_sizes, int n_in,
                              void* d_out, int out_size, void* d_ws, size_t ws_size,
                              hipStream_t stream) {
    const float* x     = (const float*)d_in[0];
    const float* Wqkv  = (const float*)d_in[1];
    const float* bqkv  = (const float*)d_in[2];
    const float* Wproj = (const float*)d_in[3];
    const float* bproj = (const float*)d_in[4];
    float* out = (float*)d_out;

    char* w = (char*)d_ws;
    const size_t SZ_X  = (size_t)4096 * 1024 * 2;  // 8 MiB (bf16)
    const size_t SZ_WQ = (size_t)3072 * 1024 * 2;
    const size_t SZ_WP = (size_t)1024 * 1024 * 2;
    u16* XH  = (u16*)w; w += SZ_X;
    u16* XL  = (u16*)w; w += SZ_X;
    u16* WQH = (u16*)w; w += SZ_WQ;
    u16* WQL = (u16*)w; w += SZ_WQ;
    u16* WPH = (u16*)w; w += SZ_WP;
    u16* WPL = (u16*)w; w += SZ_WP;
    u16* Q_s = (u16*)w; w += SZ_X;                  // [bh][s][64] scaled by log2e/8
    u16* K_b = (u16*)w; w += SZ_X;                  // [bh][s][64]
    u16* V_p = (u16*)w; w += SZ_X;                  // [bh][s/16][64][16] sigma-permuted
    u16* OHp = (u16*)w; w += SZ_X;                  // attn out hi [4096][1024]
    u16* OLp = (u16*)w; w += SZ_X;                  // attn out lo

    convert_split<<<4096, 256, 0, stream>>>(x, XH, XL, 4096 * 1024);
    transpose_split<<<dim3(96, 32), 256, 0, stream>>>(Wqkv, WQH, WQL, 1024, 3072);
    transpose_split<<<dim3(32, 32), 256, 0, stream>>>(Wproj, WPH, WPL, 1024, 1024);
    gemm_bf16x3<0><<<dim3(24, 32), 256, 0, stream>>>(XH, XL, WQH, WQL, bqkv, Q_s, K_b, V_p, nullptr);
    attn_fwd<<<512, 256, 0, stream>>>(Q_s, K_b, V_p, OHp, OLp);
    gemm_bf16x3<1><<<dim3(8, 32), 256, 0, stream>>>(OHp, OLp, WPH, WPL, bproj, nullptr, nullptr, nullptr, out);
}

// Round 12
// 193.964 us; speedup vs baseline: 1.1986x; 1.0369x over previous
//
#include <hip/hip_runtime.h>

// MultiheadAttention: bs=2, n_ctx=2048, width=1024, HEADS=16, head_dim=64, fp32 in/out.
// Pipeline: split/transpose converts -> bf16x3 QKV GEMM (gll-staged, 1 barrier/kt) ->
// swapped-QK 32x32 flash attention (LDS-shared K/V) -> bf16x3 proj GEMM.
// R12 = R7 verbatim (best measured: 194.4us). 11-round ledger: all structural alternatives
// to this configuration regressed (R8 -77%, R9 -73%, R10 -36%, R11 -42% on the QKV GEMM).

using u16 = unsigned short;
typedef __attribute__((ext_vector_type(8))) short s16x8;    // 8 bf16 = 4 VGPR (MFMA A/B frag)
typedef __attribute__((ext_vector_type(4))) float f32x4;    // 16x16 MFMA C/D frag
typedef __attribute__((ext_vector_type(16))) float f32x16;  // 32x32 MFMA C/D frag

__device__ __forceinline__ u16 f2bf(float f) {
    unsigned x = __builtin_bit_cast(unsigned, f);
    x += 0x7fffu + ((x >> 16) & 1u);            // RNE
    return (u16)(x >> 16);
}
__device__ __forceinline__ float bf2f(u16 u) {
    return __builtin_bit_cast(float, ((unsigned)u) << 16);
}
// pack two f32 -> {lo: bf16(lo), hi: bf16(hi)} with RNE — same numerics as f2bf
// (round-3 post-mortem: v_cvt_pk_bf16_f32 gave absmax 7e-4; keep the verified path).
__device__ __forceinline__ unsigned pk2bf(float lo, float hi) {
    unsigned a = __builtin_bit_cast(unsigned, lo);
    unsigned b = __builtin_bit_cast(unsigned, hi);
    a += 0x7fffu + ((a >> 16) & 1u);
    b += 0x7fffu + ((b >> 16) & 1u);
    return (a >> 16) | (b & 0xffff0000u);
}
// async global->LDS, 16B per lane; LDS dest = uniform base + lane*16 (HW rule).
__device__ __forceinline__ void gll16(const void* g, void* l) {
    __builtin_amdgcn_global_load_lds(
        (const __attribute__((address_space(1))) unsigned int*)g,
        (__attribute__((address_space(3))) unsigned int*)l, 16, 0, 0);
}

#define MFMA(a, b, c)   __builtin_amdgcn_mfma_f32_16x16x32_bf16((a), (b), (c), 0, 0, 0)
#define MFMA32(a, b, c) __builtin_amdgcn_mfma_f32_32x32x16_bf16((a), (b), (c), 0, 0, 0)

// ---------------- converts ----------------

__global__ __launch_bounds__(256) void convert_split(const float* __restrict__ in,
                                                     u16* __restrict__ H, u16* __restrict__ L, int n) {
    int i = (blockIdx.x * 256 + threadIdx.x) * 4;
    if (i >= n) return;
    float4 v = *(const float4*)(in + i);
    u16 h0 = f2bf(v.x), h1 = f2bf(v.y), h2 = f2bf(v.z), h3 = f2bf(v.w);
    ushort4 hh = { h0, h1, h2, h3 };
    ushort4 ll = { f2bf(v.x - bf2f(h0)), f2bf(v.y - bf2f(h1)), f2bf(v.z - bf2f(h2)), f2bf(v.w - bf2f(h3)) };
    *(ushort4*)(H + i) = hh;
    *(ushort4*)(L + i) = ll;
}

// W[K][N] fp32 -> WT[N][K] bf16 hi/lo.
__global__ __launch_bounds__(256) void transpose_split(const float* __restrict__ W,
                                                       u16* __restrict__ TH, u16* __restrict__ TL,
                                                       int K, int N) {
    __shared__ float st[32][33];
    int n0 = blockIdx.x * 32, k0 = blockIdx.y * 32;
    int c = threadIdx.x & 31, r8 = threadIdx.x >> 5;
#pragma unroll
    for (int i = 0; i < 4; ++i) {
        int r = r8 + i * 8;
        st[r][c] = W[(size_t)(k0 + r) * N + n0 + c];
    }
    __syncthreads();
#pragma unroll
    for (int i = 0; i < 4; ++i) {
        int r = r8 + i * 8;
        float v = st[c][r];
        u16 h = f2bf(v);
        TH[(size_t)(n0 + r) * K + k0 + c] = h;
        TL[(size_t)(n0 + r) * K + k0 + c] = f2bf(v - bf2f(h));
    }
}

// ---------------- bf16x3 GEMM (128x128 tile, BK=32, 4 waves) ----------------
// R7 structure: reg-round-trip staging, two barriers per kt. Empirical optimum for this
// problem (m97-plateau): gll/dbuf/prefetch/256^2 variants all regressed (R8-R11).
// EPI 0: QKV epilogue -> Qs (scaled log2e/8), K, Vp (sigma-permuted). EPI 1: fp32 out + bias.

template <int EPI>
__global__ __launch_bounds__(256, 2) void gemm_bf16x3(
    const u16* __restrict__ AH, const u16* __restrict__ AL,
    const u16* __restrict__ BTH, const u16* __restrict__ BTL,
    const float* __restrict__ bias,
    u16* __restrict__ Qs, u16* __restrict__ Kb, u16* __restrict__ Vp,
    float* __restrict__ Out) {
    const int K = 1024;
    __shared__ u16 sAh[128][40], sAl[128][40], sBh[128][40], sBl[128][40];

    int m0 = blockIdx.y * 128, n0 = blockIdx.x * 128;
    int tid = threadIdx.x, lane = tid & 63, wv = tid >> 6;
    int g = lane >> 4, c16 = lane & 15;
    int wm = wv >> 1, wn = wv & 1;

    f32x4 acc[4][4] = {};

    for (int kt = 0; kt < 32; ++kt) {
        int k0 = kt * 32;
        s16x8 ra[2], rla[2], rb[2], rlb[2];
#pragma unroll
        for (int i = 0; i < 2; ++i) {
            int cc = i * 256 + tid;
            int rr = cc >> 2, ko = (cc & 3) * 8;
            ra[i]  = *(const s16x8*)(AH  + (size_t)(m0 + rr) * K + k0 + ko);
            rla[i] = *(const s16x8*)(AL  + (size_t)(m0 + rr) * K + k0 + ko);
            rb[i]  = *(const s16x8*)(BTH + (size_t)(n0 + rr) * K + k0 + ko);
            rlb[i] = *(const s16x8*)(BTL + (size_t)(n0 + rr) * K + k0 + ko);
        }
        __syncthreads();
#pragma unroll
        for (int i = 0; i < 2; ++i) {
            int cc = i * 256 + tid;
            int rr = cc >> 2, ko = (cc & 3) * 8;
            *(s16x8*)&sAh[rr][ko] = ra[i];
            *(s16x8*)&sAl[rr][ko] = rla[i];
            *(s16x8*)&sBh[rr][ko] = rb[i];
            *(s16x8*)&sBl[rr][ko] = rlb[i];
        }
        __syncthreads();

        s16x8 ah[4], al[4], bh[4], bl[4];
#pragma unroll
        for (int mi = 0; mi < 4; ++mi) {
            ah[mi] = *(const s16x8*)&sAh[wm * 64 + mi * 16 + c16][g * 8];
            al[mi] = *(const s16x8*)&sAl[wm * 64 + mi * 16 + c16][g * 8];
        }
#pragma unroll
        for (int ni = 0; ni < 4; ++ni) {
            bh[ni] = *(const s16x8*)&sBh[wn * 64 + ni * 16 + c16][g * 8];
            bl[ni] = *(const s16x8*)&sBl[wn * 64 + ni * 16 + c16][g * 8];
        }
#pragma unroll
        for (int mi = 0; mi < 4; ++mi)
#pragma unroll
            for (int ni = 0; ni < 4; ++ni) {
                f32x4 c = acc[mi][ni];
                c = MFMA(ah[mi], bh[ni], c);
                c = MFMA(al[mi], bh[ni], c);
                c = MFMA(ah[mi], bl[ni], c);
                acc[mi][ni] = c;
            }
    }

    // C/D layout: col = lane&15, row = 4*(lane>>4)+reg
#pragma unroll
    for (int ni = 0; ni < 4; ++ni) {
        int col = n0 + wn * 64 + ni * 16 + c16;
        float bs = bias[col];
        if (EPI == 0) {
            int h = col / 192;
            int rm = col - h * 192;
#pragma unroll
            for (int mi = 0; mi < 4; ++mi)
#pragma unroll
                for (int r = 0; r < 4; ++r) {
                    int row = m0 + wm * 64 + mi * 16 + 4 * g + r;
                    int b = row >> 11, s = row & 2047;
                    int bh16 = b * 16 + h;
                    float val = acc[mi][ni][r] + bs;
                    if (rm < 64)
                        // 1/8 softmax scale folded with log2(e) so attn can use exp2
                        Qs[(((size_t)bh16 * 2048 + s) << 6) + rm] = f2bf(val * 0.18033688011112042f);
                    else if (rm < 128)
                        Kb[(((size_t)bh16 * 2048 + s) << 6) + rm - 64] = f2bf(val);
                    else {
                        // sigma-permuted V: Vp[bh][s/16][d][m], kv = 16*(s/16)+sigma(m),
                        // sigma(m) = (m&3) + 8*((m>>2)&1) + 4*(m>>3)
                        int d = rm - 128;
                        int kg = s >> 4, k16 = s & 15;
                        int mm = (k16 & 3) | (((k16 >> 3) & 1) << 2) | (((k16 >> 2) & 1) << 3);
                        Vp[(((size_t)bh16 * 128 + kg) * 64 + d) * 16 + mm] = f2bf(val);
                    }
                }
        } else {
#pragma unroll
            for (int mi = 0; mi < 4; ++mi)
#pragma unroll
                for (int r = 0; r < 4; ++r) {
                    int row = m0 + wm * 64 + mi * 16 + 4 * g + r;
                    Out[(size_t)row * 1024 + col] = acc[mi][ni][r] + bs;
                }
        }
    }
}

// ---------------- flash attention: LDS-shared K/V, swapped-QK 32x32 MFMA ----------------
// Block = 4 waves = 4 q-subtiles (128 q rows), each wave streams the FULL kv.
// K/V staged per 64-kv chunk into LDS in fragment-major layout [plane][lane*16B] via
// global_load_lds (lane-linear dest = conflict-free ds_read_b128; per-lane permuted source).
// Double-buffered, ONE barrier per chunk: {sync; stage(next->other buf); compute(cur)}.
__global__ __launch_bounds__(256, 2) void attn_fwd(
    const u16* __restrict__ Qs, const u16* __restrict__ Kb, const u16* __restrict__ Vp,
    u16* __restrict__ OH, u16* __restrict__ OL) {
    __shared__ u16 sKV[2][16][512];

    int id = blockIdx.x;
    int xcd = id & 7, li = id >> 3;          // 4 heads per XCD -> K/V (2MB) stays L2-resident
    int bh = xcd * 4 + (li >> 4);
    int qblk = li & 15;
    int tid = threadIdx.x, w = tid >> 6, lane = tid & 63;
    int l31 = lane & 31, h = lane >> 5;
    int q0 = (qblk * 4 + w) * 32;

    size_t base = (size_t)bh * 2048 * 64;
    size_t vbase = (size_t)bh * 131072;       // 128*64*16

    const u16* qp = Qs + base + (size_t)(q0 + l31) * 64 + 8 * h;
    s16x8 qf[4];
#pragma unroll
    for (int c = 0; c < 4; ++c) qf[c] = *(const s16x8*)(qp + 16 * c);

    const int pk0 = 2 * w, pk1 = 2 * w + 1;
    const u16* gk0 = Kb + base + (size_t)((pk0 >> 2) * 32 + l31) * 64 + 16 * (pk0 & 3) + 8 * h;
    const u16* gk1 = Kb + base + (size_t)((pk1 >> 2) * 32 + l31) * 64 + 16 * (pk1 & 3) + 8 * h;
    const u16* gv0 = Vp + vbase + (size_t)pk0 * 512 + (size_t)l31 * 16 + 8 * h;
    const u16* gv1 = Vp + vbase + (size_t)pk1 * 512 + (size_t)l31 * 16 + 8 * h;

    auto stage = [&](int buf, int jj) {
        size_t ko = (size_t)jj * 4096;        // 64 kv rows * 64 d
        gll16(gk0 + ko, &sKV[buf][pk0][0]);
        gll16(gk1 + ko, &sKV[buf][pk1][0]);
        gll16(gv0 + ko, &sKV[buf][8 + pk0][0]);
        gll16(gv1 + ko, &sKV[buf][8 + pk1][0]);
    };

    f32x16 o0 = {}, o1 = {};
    float m = -1e30f, ls = 0.f;
    const int lo = lane * 8;

    stage(0, 0);

    for (int jj = 0; jj < 32; ++jj) {
        int cur = jj & 1;
        __syncthreads();
        if (jj < 31) stage(cur ^ 1, jj + 1);

        s16x8 kf[8], vf[8];
#pragma unroll
        for (int i = 0; i < 8; ++i) {
            kf[i] = *(const s16x8*)&sKV[cur][i][lo];
            vf[i] = *(const s16x8*)&sKV[cur][8 + i][lo];
        }

        f32x16 s0 = {}, s1 = {};
        __builtin_amdgcn_s_setprio(1);
        s0 = MFMA32(kf[0], qf[0], s0);
        s0 = MFMA32(kf[1], qf[1], s0);
        s0 = MFMA32(kf[2], qf[2], s0);
        s0 = MFMA32(kf[3], qf[3], s0);
        s1 = MFMA32(kf[4], qf[0], s1);
        s1 = MFMA32(kf[5], qf[1], s1);
        s1 = MFMA32(kf[6], qf[2], s1);
        s1 = MFMA32(kf[7], qf[3], s1);
        __builtin_amdgcn_s_setprio(0);

        float t0 = fmaxf(s0[0], s1[0]), t1 = fmaxf(s0[1], s1[1]);
        float t2 = fmaxf(s0[2], s1[2]), t3 = fmaxf(s0[3], s1[3]);
#pragma unroll
        for (int r = 4; r < 16; r += 4) {
            t0 = fmaxf(t0, fmaxf(s0[r], s1[r]));
            t1 = fmaxf(t1, fmaxf(s0[r + 1], s1[r + 1]));
            t2 = fmaxf(t2, fmaxf(s0[r + 2], s1[r + 2]));
            t3 = fmaxf(t3, fmaxf(s0[r + 3], s1[r + 3]));
        }
        float pmax = fmaxf(fmaxf(t0, t1), fmaxf(t2, t3));
        pmax = fmaxf(pmax, __shfl_xor(pmax, 32));

        if (!__all(pmax <= m + 8.f)) {          // defer-max (T13), log2 units
            float mn = fmaxf(m, pmax);
            float f = __builtin_amdgcn_exp2f(m - mn);
            m = mn;
            ls *= f;
#pragma unroll
            for (int r = 0; r < 16; ++r) {
                float fb = __shfl(f, (r & 3) + 8 * (r >> 2) + 4 * h);
                o0[r] *= fb;
                o1[r] *= fb;
            }
        }

        float a0 = 0.f, a1 = 0.f, a2 = 0.f, a3 = 0.f;
#pragma unroll
        for (int r = 0; r < 16; r += 4) {
            s0[r]     = __builtin_amdgcn_exp2f(s0[r] - m);     a0 += s0[r];
            s0[r + 1] = __builtin_amdgcn_exp2f(s0[r + 1] - m); a1 += s0[r + 1];
            s0[r + 2] = __builtin_amdgcn_exp2f(s0[r + 2] - m); a2 += s0[r + 2];
            s0[r + 3] = __builtin_amdgcn_exp2f(s0[r + 3] - m); a3 += s0[r + 3];
            s1[r]     = __builtin_amdgcn_exp2f(s1[r] - m);     a0 += s1[r];
            s1[r + 1] = __builtin_amdgcn_exp2f(s1[r + 1] - m); a1 += s1[r + 1];
            s1[r + 2] = __builtin_amdgcn_exp2f(s1[r + 2] - m); a2 += s1[r + 2];
            s1[r + 3] = __builtin_amdgcn_exp2f(s1[r + 3] - m); a3 += s1[r + 3];
        }
        float sm = (a0 + a1) + (a2 + a3);
        sm += __shfl_xor(sm, 32);
        ls += sm;

        union { s16x8 v8; unsigned u[4]; } p00, p01, p10, p11;
#pragma unroll
        for (int k = 0; k < 4; ++k) {
            p00.u[k] = pk2bf(s0[2 * k], s0[2 * k + 1]);
            p01.u[k] = pk2bf(s0[8 + 2 * k], s0[9 + 2 * k]);
            p10.u[k] = pk2bf(s1[2 * k], s1[2 * k + 1]);
            p11.u[k] = pk2bf(s1[8 + 2 * k], s1[9 + 2 * k]);
        }

        __builtin_amdgcn_s_setprio(1);
        o0 = MFMA32(p00.v8, vf[0], o0);
        o1 = MFMA32(p00.v8, vf[1], o1);
        o0 = MFMA32(p01.v8, vf[2], o0);
        o1 = MFMA32(p01.v8, vf[3], o1);
        o0 = MFMA32(p10.v8, vf[4], o0);
        o1 = MFMA32(p10.v8, vf[5], o1);
        o0 = MFMA32(p11.v8, vf[6], o0);
        o1 = MFMA32(p11.v8, vf[7], o1);
        __builtin_amdgcn_s_setprio(0);
    }

    int b = bh >> 4, hh = bh & 15;
    float inv = 1.0f / ls;
#pragma unroll
    for (int r = 0; r < 16; ++r) {
        int cr = (r & 3) + 8 * (r >> 2) + 4 * h;
        float fb = __shfl(inv, cr);
        int row = q0 + cr;
        size_t idx = ((size_t)(b * 2048 + row)) * 1024 + hh * 64 + l31;
        float v0 = o0[r] * fb, v1 = o1[r] * fb;
        u16 h0 = f2bf(v0);
        OH[idx] = h0;
        OL[idx] = f2bf(v0 - bf2f(h0));
        u16 h1 = f2bf(v1);
        OH[idx + 32] = h1;
        OL[idx + 32] = f2bf(v1 - bf2f(h1));
    }
}

// ---------------- launch ----------------

extern "C" void kernel_launch(void* const* d_in, const int* in_sizes, int n_in,
                              void* d_out, int out_size, void* d_ws, size_t ws_size,
                              hipStream_t stream) {
    const float* x     = (const float*)d_in[0];
    const float* Wqkv  = (const float*)d_in[1];
    const float* bqkv  = (const float*)d_in[2];
    const float* Wproj = (const float*)d_in[3];
    const float* bproj = (const float*)d_in[4];
    float* out = (float*)d_out;

    char* w = (char*)d_ws;
    const size_t SZ_X  = (size_t)4096 * 1024 * 2;  // 8 MiB (bf16)
    const size_t SZ_WQ = (size_t)3072 * 1024 * 2;
    const size_t SZ_WP = (size_t)1024 * 1024 * 2;
    u16* XH  = (u16*)w; w += SZ_X;
    u16* XL  = (u16*)w; w += SZ_X;
    u16* WQH = (u16*)w; w += SZ_WQ;
    u16* WQL = (u16*)w; w += SZ_WQ;
    u16* WPH = (u16*)w; w += SZ_WP;
    u16* WPL = (u16*)w; w += SZ_WP;
    u16* Q_s = (u16*)w; w += SZ_X;                  // [bh][s][64] scaled by log2e/8
    u16* K_b = (u16*)w; w += SZ_X;                  // [bh][s][64]
    u16* V_p = (u16*)w; w += SZ_X;                  // [bh][s/16][64][16] sigma-permuted
    u16* OHp = (u16*)w; w += SZ_X;                  // attn out hi [4096][1024]
    u16* OLp = (u16*)w; w += SZ_X;                  // attn out lo

    convert_split<<<4096, 256, 0, stream>>>(x, XH, XL, 4096 * 1024);
    transpose_split<<<dim3(96, 32), 256, 0, stream>>>(Wqkv, WQH, WQL, 1024, 3072);
    transpose_split<<<dim3(32, 32), 256, 0, stream>>>(Wproj, WPH, WPL, 1024, 1024);
    gemm_bf16x3<0><<<dim3(24, 32), 256, 0, stream>>>(XH, XL, WQH, WQL, bqkv, Q_s, K_b, V_p, nullptr);
    attn_fwd<<<512, 256, 0, stream>>>(Q_s, K_b, V_p, OHp, OLp);
    gemm_bf16x3<1><<<dim3(8, 32), 256, 0, stream>>>(OHp, OLp, WPH, WPL, bproj, nullptr, nullptr, nullptr, out);
}